// Round 6
// baseline (11686.018 us; speedup 1.0000x reference)
//
#include <hip/hip_runtime.h>

#define N_EXC  512
#define NTOT   640
#define NIN    16
#define BATCH  64
#define TSTEPS 1000
#define CHUNK  160      // units per block
#define NBLKG  4        // blocks per batch sample
#define THREADS 512
#define NPT    10       // n per thread (16 ti-groups * 10 = 160)
#define KPT    20       // k per thread (32 tj-groups * 20 = 640)
#define NTJ    32
// ALPHA = 0.5, NOISE_SCALE = 0.01

typedef float f32x4 __attribute__((ext_vector_type(4)));
typedef float f32x2 __attribute__((ext_vector_type(2)));

// ---------------------------------------------------------------------------
// JAX threefry2x32, key = jax.random.key(42) -> (0, 42); partitionable bits
// ---------------------------------------------------------------------------
__device__ __forceinline__ void threefry_0_42(unsigned x0, unsigned x1,
                                              unsigned& o0, unsigned& o1) {
    const unsigned ks1 = 42u;
    const unsigned ks2 = 0x1BD11BDAu ^ 42u;
    x0 += 0u; x1 += ks1;
#define TF_RND(r) { x0 += x1; x1 = (x1 << (r)) | (x1 >> (32 - (r))); x1 ^= x0; }
    TF_RND(13) TF_RND(15) TF_RND(26) TF_RND(6)
    x0 += ks1; x1 += ks2 + 1u;
    TF_RND(17) TF_RND(29) TF_RND(16) TF_RND(24)
    x0 += ks2; x1 += 0u + 2u;
    TF_RND(13) TF_RND(15) TF_RND(26) TF_RND(6)
    x0 += 0u; x1 += ks1 + 3u;
    TF_RND(17) TF_RND(29) TF_RND(16) TF_RND(24)
    x0 += ks1; x1 += ks2 + 4u;
    TF_RND(13) TF_RND(15) TF_RND(26) TF_RND(6)
    x0 += ks2; x1 += 0u + 5u;
#undef TF_RND
    o0 = x0; o1 = x1;
}

__device__ __forceinline__ unsigned jax_bits_partitionable(unsigned idx) {
    unsigned o0, o1;
    threefry_0_42(0u, idx, o0, o1);
    return o0 ^ o1;
}

// bits -> jax.random.normal sample scaled by NOISE_SCALE*sqrt(ALPHA), f32-exact
__device__ __forceinline__ float noise_from_bits(unsigned bits) {
    float f = __uint_as_float(0x3f800000u | (bits >> 9)) - 1.0f;   // [0,1)
    float u = __fadd_rn(__fmul_rn(f, 2.0f), -0.99999994f);
    u = fmaxf(-0.99999994f, u);
    float w = -log1pf(-__fmul_rn(u, u));
    float p;
    if (w < 5.0f) {
        float ww = w - 2.5f;
        p = 2.81022636e-08f;
        p = fmaf(p, ww, 3.43273939e-07f);
        p = fmaf(p, ww, -3.5233877e-06f);
        p = fmaf(p, ww, -4.39150654e-06f);
        p = fmaf(p, ww, 0.00021858087f);
        p = fmaf(p, ww, -0.00125372503f);
        p = fmaf(p, ww, -0.00417768164f);
        p = fmaf(p, ww, 0.246640727f);
        p = fmaf(p, ww, 1.50140941f);
    } else {
        float ww = sqrtf(w) - 3.0f;
        p = -0.000200214257f;
        p = fmaf(p, ww, 0.000100950558f);
        p = fmaf(p, ww, 0.00134934322f);
        p = fmaf(p, ww, -0.00367342844f);
        p = fmaf(p, ww, 0.00573950773f);
        p = fmaf(p, ww, -0.0076224613f);
        p = fmaf(p, ww, 0.00943887047f);
        p = fmaf(p, ww, 1.00167406f);
        p = fmaf(p, ww, 2.83297682f);
    }
    float z = 1.41421354f * (p * u);
    return (0.01f * 0.70710677f) * z;
}

#define FOR20(M) M(0) M(1) M(2) M(3) M(4) M(5) M(6) M(7) M(8) M(9) \
                 M(10) M(11) M(12) M(13) M(14) M(15) M(16) M(17) M(18) M(19)

// ---------------------------------------------------------------------------
// Persistent kernel: 256 blocks = 4 chunk-blocks x 64 batches.
// Weights in NAMED ext_vector registers (mem2reg-promotable; round 5's
// w[200] array fell to scratch via SROA bailout -> 128 VGPR + spill traffic).
// Thread (ti,tj) = (tid&15, tid>>4) owns n in [nbase+ti*10, +10), k in
// [tj*20, +20): 20 x (f32x4,f32x4,f32x2) named weight vectors over n.
// ---------------------------------------------------------------------------
__global__ __launch_bounds__(THREADS, 1)
void eirnn_sync(const float* __restrict__ inputs, const float* __restrict__ Wraw,
                const float* __restrict__ W_in, const float* __restrict__ W_out,
                const float* __restrict__ b_out, float* __restrict__ rates_out,
                float* __restrict__ outs_out, unsigned* __restrict__ flags,
                float* __restrict__ rbuf) {
    const int b   = blockIdx.x & 63;
    const int g   = blockIdx.x >> 6;
    const int tid = threadIdx.x;
    const int ti  = tid & 15;        // n-group (0..15)
    const int tj  = tid >> 4;        // k-group (0..31)
    const int nbase = g * CHUNK;
    const int nloc  = nbase + ti * NPT;   // first owned n (global id)
    const int kbase = tj * KPT;           // first owned k

    __shared__ __align__(16) float r_all[NTOT];
    __shared__ float part[NTJ * CHUNK];
    __shared__ float win_s[CHUNK * 17];
    __shared__ float u_s[NIN];
    __shared__ float red0[8], red1[8];

    // ---- named weight registers ----
#define DECLW(K) f32x4 wA##K, wB##K; f32x2 wC##K;
    FOR20(DECLW)
#undef DECLW

    // ---- one-time: load weight panel (dale applied on the fly) ----
#define LOADW(K) {                                                          \
        const int k_ = kbase + (K);                                         \
        const float sg_ = (k_ < N_EXC) ? 1.0f : -1.0f;                      \
        const float* c_ = Wraw + (size_t)nloc * NTOT + k_;                  \
        float v0 = fabsf(c_[0 * NTOT]) * sg_; if (k_ == nloc + 0) v0 = 0.f; \
        float v1 = fabsf(c_[1 * NTOT]) * sg_; if (k_ == nloc + 1) v1 = 0.f; \
        float v2 = fabsf(c_[2 * NTOT]) * sg_; if (k_ == nloc + 2) v2 = 0.f; \
        float v3 = fabsf(c_[3 * NTOT]) * sg_; if (k_ == nloc + 3) v3 = 0.f; \
        float v4 = fabsf(c_[4 * NTOT]) * sg_; if (k_ == nloc + 4) v4 = 0.f; \
        float v5 = fabsf(c_[5 * NTOT]) * sg_; if (k_ == nloc + 5) v5 = 0.f; \
        float v6 = fabsf(c_[6 * NTOT]) * sg_; if (k_ == nloc + 6) v6 = 0.f; \
        float v7 = fabsf(c_[7 * NTOT]) * sg_; if (k_ == nloc + 7) v7 = 0.f; \
        float v8 = fabsf(c_[8 * NTOT]) * sg_; if (k_ == nloc + 8) v8 = 0.f; \
        float v9 = fabsf(c_[9 * NTOT]) * sg_; if (k_ == nloc + 9) v9 = 0.f; \
        wA##K = (f32x4){v0, v1, v2, v3};                                    \
        wB##K = (f32x4){v4, v5, v6, v7};                                    \
        wC##K = (f32x2){v8, v9};                                            \
    }
    FOR20(LOADW)
#undef LOADW

    // W_in chunk -> LDS (padded stride 17)
    for (int i = tid; i < CHUNK * NIN; i += THREADS) {
        int o = i >> 4, j = i & 15;
        win_s[o * 17 + j] = W_in[(nbase + o) * NIN + j];
    }
    // readout weights: block g==0 computes y; tid covers exactly r[:512]
    float wo0 = 0.0f, wo1 = 0.0f;
    if (g == 0) { wo0 = W_out[tid]; wo1 = W_out[N_EXC + tid]; }
    const float bo0 = b_out[0], bo1 = b_out[1];

    const float* inp_b = inputs    + (size_t)b * TSTEPS * NIN;
    float* rates_b     = rates_out + (size_t)b * TSTEPS * NTOT;
    float* outs_b      = outs_out  + (size_t)b * TSTEPS * 2;
    unsigned* myflag   = flags + (b * NBLKG + g);

    float x = 0.0f;   // owner state for tid < CHUNK
    __syncthreads();  // win_s ready

    for (int t = 0; t < TSTEPS; ++t) {
        // ---- phase A: rates from current x; publish own chunk -------------
        if (tid < CHUNK) {
            float r = fmaxf(x, 0.0f) + log1pf(expf(-fabsf(x)));
            r_all[nbase + tid] = r;
            rates_b[t * NTOT + nbase + tid] = r;
            float* dst = rbuf + ((size_t)((t & 1) * BATCH + b) * NBLKG + g) * CHUNK + tid;
            __hip_atomic_store(dst, r, __ATOMIC_RELAXED, __HIP_MEMORY_SCOPE_AGENT);
        } else if (tid < CHUNK + NIN) {
            u_s[tid - CHUNK] = inp_b[t * NIN + (tid - CHUNK)];
        }
        __syncthreads();   // drains owners' rbuf stores before flag

        if (tid == 0)
            __hip_atomic_store(myflag, (unsigned)(t + 1), __ATOMIC_RELEASE,
                               __HIP_MEMORY_SCOPE_AGENT);
        if (tid >= 1 && tid < NBLKG) {          // 3 pollers
            int p = tid - 1;
            int gg = p + (p >= g ? 1 : 0);
            unsigned* f = flags + b * NBLKG + gg;
            while (__hip_atomic_load(f, __ATOMIC_ACQUIRE, __HIP_MEMORY_SCOPE_AGENT)
                   < (unsigned)(t + 1)) {
                __builtin_amdgcn_s_sleep(1);
            }
        }
        __syncthreads();

        // ---- phase B: pull remote chunks into r_all ------------------------
        if (tid < 3 * CHUNK) {
            int p = tid / CHUNK;
            int gg = p + (p >= g ? 1 : 0);
            int o = tid - p * CHUNK;
            const float* src = rbuf + ((size_t)((t & 1) * BATCH + b) * NBLKG + gg) * CHUNK + o;
            r_all[gg * CHUNK + o] =
                __hip_atomic_load(src, __ATOMIC_RELAXED, __HIP_MEMORY_SCOPE_AGENT);
        }
        __syncthreads();

        // ---- phase C: register-resident GEMV (vectors span n; rk broadcast)
        {
            f32x4 accA = {0.f, 0.f, 0.f, 0.f};
            f32x4 accB = {0.f, 0.f, 0.f, 0.f};
            f32x2 accC = {0.f, 0.f};
#define FMAK(K) { float rk_ = r_all[kbase + (K)];                           \
                  accA += wA##K * rk_; accB += wB##K * rk_;                 \
                  accC += wC##K * rk_; }
            FOR20(FMAK)
#undef FMAK
            float* pp = &part[tj * CHUNK + ti * NPT];   // 8B-aligned (NPT even)
            ((f32x2*)pp)[0] = (f32x2){accA.x, accA.y};
            ((f32x2*)pp)[1] = (f32x2){accA.z, accA.w};
            ((f32x2*)pp)[2] = (f32x2){accB.x, accB.y};
            ((f32x2*)pp)[3] = (f32x2){accB.z, accB.w};
            ((f32x2*)pp)[4] = accC;
        }

        // readout partials on g==0 (r_all is complete r_t)
        if (g == 0) {
            float rr = r_all[tid];
            float p0 = rr * wo0, p1 = rr * wo1;
#pragma unroll
            for (int off = 32; off; off >>= 1) {
                p0 += __shfl_down(p0, off);
                p1 += __shfl_down(p1, off);
            }
            if ((tid & 63) == 0) { red0[tid >> 6] = p0; red1[tid >> 6] = p1; }
        }
        __syncthreads();

        // ---- phase D: owner state update ----------------------------------
        if (tid < CHUNK) {
            float rec = 0.0f;
#pragma unroll
            for (int j = 0; j < NTJ; ++j) rec += part[j * CHUNK + tid];
            float ext = 0.0f;
#pragma unroll
            for (int j = 0; j < NIN; ++j)
                ext = fmaf(win_s[tid * 17 + j], u_s[j], ext);
            unsigned idx = (unsigned)(t * (BATCH * NTOT) + b * NTOT + (nbase + tid));
            float eps = noise_from_bits(jax_bits_partitionable(idx));
            x = (0.5f * x + 0.5f * (rec + ext)) + eps;
        }
        if (g == 0 && tid == 0) {
            float y0 = bo0, y1 = bo1;
#pragma unroll
            for (int wv = 0; wv < 8; ++wv) { y0 += red0[wv]; y1 += red1[wv]; }
            outs_b[t * 2 + 0] = y0;
            outs_b[t * 2 + 1] = y1;
        }
        __syncthreads();   // protect r_all/part/u_s/red before next iteration
    }
}

// ---------------------------------------------------------------------------
extern "C" void kernel_launch(void* const* d_in, const int* in_sizes, int n_in,
                              void* d_out, int out_size, void* d_ws, size_t ws_size,
                              hipStream_t stream) {
    const float* inputs = (const float*)d_in[0];   // [64,1000,16]
    const float* Wraw   = (const float*)d_in[1];   // [640,640]
    const float* W_in   = (const float*)d_in[2];   // [640,16]
    const float* W_out  = (const float*)d_in[3];   // [2,512]
    const float* b_out  = (const float*)d_in[4];   // [2]

    float* out   = (float*)d_out;
    float* rates = out;                                    // [64,1000,640]
    float* outs  = out + (size_t)BATCH * TSTEPS * NTOT;    // [64,1000,2]

    unsigned* flags = (unsigned*)d_ws;                     // 64*4 u32, zeroed
    float* rbuf = (float*)((char*)d_ws + 4096);            // [2][64][4][160] f32

    hipMemsetAsync(d_ws, 0, 4096, stream);
    eirnn_sync<<<dim3(NBLKG * BATCH), dim3(THREADS), 0, stream>>>(
        inputs, Wraw, W_in, W_out, b_out, rates, outs, flags, rbuf);
}